// Round 2
// baseline (2575.001 us; speedup 1.0000x reference)
//
#include <hip/hip_runtime.h>
#include <math.h>

#define NN 100000   // nodes
#define NE 1600000  // edges
#define NG 2048     // graphs
#define FIN 33      // input features
#define DD 256      // hidden dim

// ---- bf16 helpers (bit ops, RNE) ----
__device__ __forceinline__ float b2f(unsigned short u){
    union { unsigned int i; float f; } c; c.i = ((unsigned int)u) << 16; return c.f;
}
__device__ __forceinline__ unsigned short f2b(float f){
    union { float f; unsigned int u; } c; c.f = f;
    unsigned int r = c.u + 0x7fffu + ((c.u >> 16) & 1u);   // round-nearest-even
    return (unsigned short)(r >> 16);
}

__device__ __forceinline__ float gelu_tanh(float x){
    float x3 = x * x * x;
    float t = tanhf(0.7978845608028654f * (x + 0.044715f * x3));
    return 0.5f * x * (1.0f + t);
}

// ---------------- CSR build ----------------
__global__ void k_count(const int* __restrict__ dst, int* __restrict__ deg){
    int e = blockIdx.x * 256 + threadIdx.x;
    if(e < NE) atomicAdd(&deg[dst[e]], 1);
}

__global__ void k_scan1(const int* __restrict__ deg, int* __restrict__ rs, int* __restrict__ bsum){
    __shared__ int s[256];
    int t = threadIdx.x, i = blockIdx.x * 256 + t;
    int v = (i < NN) ? deg[i] : 0;
    s[t] = v; __syncthreads();
    for(int off = 1; off < 256; off <<= 1){
        int u = (t >= off) ? s[t - off] : 0;
        __syncthreads();
        s[t] += u;
        __syncthreads();
    }
    if(i < NN) rs[i] = s[t] - v;          // exclusive, intra-block
    if(t == 255) bsum[blockIdx.x] = s[255];
}

__global__ void k_scan2(int* __restrict__ bsum, int nb){
    __shared__ int s[512];
    int t = threadIdx.x;
    int v = (t < nb) ? bsum[t] : 0;
    s[t] = v; __syncthreads();
    for(int off = 1; off < 512; off <<= 1){
        int u = (t >= off) ? s[t - off] : 0;
        __syncthreads();
        s[t] += u;
        __syncthreads();
    }
    if(t < nb) bsum[t] = s[t] - v;        // exclusive block offsets
}

__global__ void k_scan3(int* __restrict__ rs, const int* __restrict__ bsum, int* __restrict__ cursor){
    int i = blockIdx.x * 256 + threadIdx.x;
    if(i < NN){
        int r = rs[i] + bsum[i >> 8];
        rs[i] = r;
        cursor[i] = r;
    }
}

__global__ void k_fill(const int* __restrict__ src, const int* __restrict__ dst,
                       int* __restrict__ cursor, int* __restrict__ esrc){
    int e = blockIdx.x * 256 + threadIdx.x;
    if(e < NE){
        int d = dst[e];
        int p = atomicAdd(&cursor[d], 1);
        esrc[p] = src[e];
    }
}

// ---------------- aggregation (gather via CSR) ----------------
// layer 0: f32 input [NN,33] -> f32 agg [NN,33]
__global__ void k_agg33(const float* __restrict__ x, const int* __restrict__ rs,
                        const int* __restrict__ deg, const int* __restrict__ esrc,
                        float* __restrict__ agg){
    int w = (blockIdx.x * blockDim.x + threadIdx.x) >> 6;
    int lane = threadIdx.x & 63;
    if(w >= NN) return;
    int start = rs[w], cnt = deg[w];
    float acc = 0.f;
    for(int j = 0; j < cnt; j++){
        int s = esrc[start + j];
        if(lane < FIN) acc += x[(size_t)s * FIN + lane];
    }
    if(lane < FIN) agg[(size_t)w * FIN + lane] = acc;
}

// layers 1-3: bf16 h [NN,256] -> bf16 agg [NN,256], f32 register accumulate
__global__ void k_agg256(const unsigned short* __restrict__ h, const int* __restrict__ rs,
                         const int* __restrict__ deg, const int* __restrict__ esrc,
                         unsigned short* __restrict__ agg){
    int w = (blockIdx.x * blockDim.x + threadIdx.x) >> 6;
    int lane = threadIdx.x & 63;
    if(w >= NN) return;
    int start = rs[w], cnt = deg[w];
    float a0 = 0.f, a1 = 0.f, a2 = 0.f, a3 = 0.f;
    const unsigned short* hp = h + lane * 4;
    for(int j = 0; j < cnt; j++){
        int s = esrc[start + j];
        ushort4 v = *(const ushort4*)(hp + (size_t)s * DD);
        a0 += b2f(v.x); a1 += b2f(v.y); a2 += b2f(v.z); a3 += b2f(v.w);
    }
    ushort4 o; o.x = f2b(a0); o.y = f2b(a1); o.z = f2b(a2); o.w = f2b(a3);
    *(ushort4*)(agg + (size_t)w * DD + lane * 4) = o;
}

// ---------------- fused dual GEMM + bias + GELU ----------------
// out[i][j] = gelu( sum_k A0[i,k]*B0[k,j] + A1[i,k]*B1[k,j] + bias[j] ) -> bf16
// TA = float (layer 0, K=33) or unsigned short (bf16, K=256)
#define BM 64
#define BN 64
#define BKK 16

template<typename TA>
__global__ __launch_bounds__(256) void k_gemm_fused(
    const TA* __restrict__ A0, const TA* __restrict__ A1,
    const float* __restrict__ B0, const float* __restrict__ B1,
    const float* __restrict__ bias, unsigned short* __restrict__ out, int K)
{
    __shared__ float As0[BKK][BM + 4];
    __shared__ float As1[BKK][BM + 4];
    __shared__ float Bs0[BKK][BN + 4];
    __shared__ float Bs1[BKK][BN + 4];

    int t  = threadIdx.x;
    int tx = t & 15, ty = t >> 4;
    int i0 = blockIdx.x * BM;
    int j0 = blockIdx.y * BN;

    int am = t >> 2;          // 0..63
    int ak = (t & 3) * 4;     // 0,4,8,12
    int bk = t >> 4;          // 0..15
    int bj = (t & 15) * 4;    // 0..60

    float acc[4][4] = {};

    for(int k0 = 0; k0 < K; k0 += BKK){
        // --- A tiles (transposed into LDS: As[k][m]) ---
        if constexpr (sizeof(TA) == 2){
            // bf16 path: K % 16 == 0 guaranteed (K=256)
            int gi = i0 + am;
            int gk = k0 + ak;
            float v0[4] = {0,0,0,0}, v1[4] = {0,0,0,0};
            if(gi < NN){
                ushort4 u0 = *(const ushort4*)(A0 + (size_t)gi * K + gk);
                ushort4 u1 = *(const ushort4*)(A1 + (size_t)gi * K + gk);
                v0[0]=b2f(u0.x); v0[1]=b2f(u0.y); v0[2]=b2f(u0.z); v0[3]=b2f(u0.w);
                v1[0]=b2f(u1.x); v1[1]=b2f(u1.y); v1[2]=b2f(u1.z); v1[3]=b2f(u1.w);
            }
            #pragma unroll
            for(int q = 0; q < 4; q++){ As0[ak+q][am] = v0[q]; As1[ak+q][am] = v1[q]; }
        } else {
            // f32 scalar path with full bounds checks (K=33)
            #pragma unroll
            for(int q = 0; q < 4; q++){
                int k  = ak + q;
                int gi = i0 + am;
                int gk = k0 + k;
                float v0 = 0.f, v1 = 0.f;
                if(gi < NN && gk < K){
                    v0 = (float)A0[(size_t)gi * K + gk];
                    v1 = (float)A1[(size_t)gi * K + gk];
                }
                As0[k][am] = v0;
                As1[k][am] = v1;
            }
        }
        // --- B tiles (f32 weights) ---
        {
            int gk = k0 + bk;
            float4 v0 = {0,0,0,0}, v1 = {0,0,0,0};
            if(gk < K){
                v0 = *(const float4*)(B0 + (size_t)gk * DD + j0 + bj);
                v1 = *(const float4*)(B1 + (size_t)gk * DD + j0 + bj);
            }
            *(float4*)&Bs0[bk][bj] = v0;
            *(float4*)&Bs1[bk][bj] = v1;
        }
        __syncthreads();

        #pragma unroll
        for(int k = 0; k < BKK; k++){
            float a0[4], a1[4], b0[4], b1[4];
            #pragma unroll
            for(int m = 0; m < 4; m++){ a0[m] = As0[k][ty*4 + m]; a1[m] = As1[k][ty*4 + m]; }
            #pragma unroll
            for(int n = 0; n < 4; n++){ b0[n] = Bs0[k][tx*4 + n]; b1[n] = Bs1[k][tx*4 + n]; }
            #pragma unroll
            for(int m = 0; m < 4; m++)
                #pragma unroll
                for(int n = 0; n < 4; n++)
                    acc[m][n] += a0[m]*b0[n] + a1[m]*b1[n];
        }
        __syncthreads();
    }

    #pragma unroll
    for(int m = 0; m < 4; m++){
        int gi = i0 + ty*4 + m;
        if(gi >= NN) continue;
        #pragma unroll
        for(int n = 0; n < 4; n++){
            int gj = j0 + tx*4 + n;
            float v = acc[m][n] + bias[gj];
            out[(size_t)gi * DD + gj] = f2b(gelu_tanh(v));
        }
    }
}

// ---------------- pooling + output head ----------------
__global__ void k_pool(const unsigned short* __restrict__ h, const int* __restrict__ batch,
                       const float* __restrict__ wout, float* __restrict__ gsum,
                       int* __restrict__ gcnt){
    int w = (blockIdx.x * blockDim.x + threadIdx.x) >> 6;
    int lane = threadIdx.x & 63;
    if(w >= NN) return;
    ushort4 hv = *(const ushort4*)(h + (size_t)w * DD + lane * 4);
    float4 wv = *(const float4*)(wout + lane * 4);
    float d = b2f(hv.x)*wv.x + b2f(hv.y)*wv.y + b2f(hv.z)*wv.z + b2f(hv.w)*wv.w;
    for(int off = 32; off > 0; off >>= 1) d += __shfl_down(d, off);
    if(lane == 0){
        int g = batch[w];
        atomicAdd(&gsum[g], d);
        atomicAdd(&gcnt[g], 1);
    }
}

__global__ void k_final(const float* __restrict__ gsum, const int* __restrict__ gcnt,
                        const float* __restrict__ bout, float* __restrict__ out){
    int g = blockIdx.x * 256 + threadIdx.x;
    if(g < NG) out[g] = gsum[g] / fmaxf((float)gcnt[g], 1.f) + bout[0];
}

// ---------------- launch ----------------
extern "C" void kernel_launch(void* const* d_in, const int* in_sizes, int n_in,
                              void* d_out, int out_size, void* d_ws, size_t ws_size,
                              hipStream_t stream){
    const float* x       = (const float*)d_in[0];
    const int*   ei      = (const int*)d_in[1];
    const int*   src     = ei;        // edge_index[0]
    const int*   dst     = ei + NE;   // edge_index[1]
    const int*   batch   = (const int*)d_in[2];
    const float* w_rel0  = (const float*)d_in[3];
    const float* b_rel0  = (const float*)d_in[4];
    const float* w_root0 = (const float*)d_in[5];
    const float* w_rel1  = (const float*)d_in[6];
    const float* b_rel1  = (const float*)d_in[7];
    const float* w_root1 = (const float*)d_in[8];
    const float* w_rel2  = (const float*)d_in[9];
    const float* b_rel2  = (const float*)d_in[10];
    const float* w_root2 = (const float*)d_in[11];
    const float* w_rel3  = (const float*)d_in[12];
    const float* b_rel3  = (const float*)d_in[13];
    const float* w_root3 = (const float*)d_in[14];
    const float* w_out   = (const float*)d_in[15];
    const float* b_out   = (const float*)d_in[16];
    float* out = (float*)d_out;

    // workspace layout: ~161.5 MB total (was 315 MB in round 0 -> suspected OOB crash)
    char* ws = (char*)d_ws;
    size_t off = 0;
    auto alloc = [&](size_t bytes) -> void* {
        void* p = ws + off;
        off = (off + bytes + 255) & ~(size_t)255;
        return p;
    };
    unsigned short* hA  = (unsigned short*)alloc((size_t)NN * DD * 2);  // 51.2 MB
    unsigned short* hB  = (unsigned short*)alloc((size_t)NN * DD * 2);  // 51.2 MB
    unsigned short* agg = (unsigned short*)alloc((size_t)NN * DD * 2);  // 51.2 MB (layer0: f32 [NN,33] = 13.2 MB fits)
    int*   deg  = (int*)alloc((size_t)NN * 4);
    int*   rs   = (int*)alloc((size_t)NN * 4);
    int*   cur  = (int*)alloc((size_t)NN * 4);
    int*   esrc = (int*)alloc((size_t)NE * 4);
    int*   bsum = (int*)alloc(512 * 4);
    float* gsum = (float*)alloc((size_t)NG * 4);
    int*   gcnt = (int*)alloc((size_t)NG * 4);
    (void)ws_size; (void)in_sizes; (void)n_in; (void)out_size;
    float* aggF = (float*)agg;   // layer-0 f32 view

    // CSR build (once per call, reused by all 4 layers)
    hipMemsetAsync(deg, 0, (size_t)NN * 4, stream);
    k_count<<<(NE + 255) / 256, 256, 0, stream>>>(dst, deg);
    int nb = (NN + 255) / 256;
    k_scan1<<<nb, 256, 0, stream>>>(deg, rs, bsum);
    k_scan2<<<1, 512, 0, stream>>>(bsum, nb);
    k_scan3<<<nb, 256, 0, stream>>>(rs, bsum, cur);
    k_fill<<<(NE + 255) / 256, 256, 0, stream>>>(src, dst, cur, esrc);

    int aggGrid = (NN + 3) / 4;              // 4 waves per 256-thread block
    dim3 gg((NN + BM - 1) / BM, DD / BN);

    // layer 0: aggregate 33-dim f32 input, fused dual GEMM K=33 -> bf16 hA
    k_agg33<<<aggGrid, 256, 0, stream>>>(x, rs, deg, esrc, aggF);
    k_gemm_fused<float><<<gg, 256, 0, stream>>>(aggF, x, w_rel0, w_root0, b_rel0, hA, FIN);
    // layers 1..3 (bf16 h, f32 accumulate)
    k_agg256<<<aggGrid, 256, 0, stream>>>(hA, rs, deg, esrc, agg);
    k_gemm_fused<unsigned short><<<gg, 256, 0, stream>>>(agg, hA, w_rel1, w_root1, b_rel1, hB, DD);
    k_agg256<<<aggGrid, 256, 0, stream>>>(hB, rs, deg, esrc, agg);
    k_gemm_fused<unsigned short><<<gg, 256, 0, stream>>>(agg, hB, w_rel2, w_root2, b_rel2, hA, DD);
    k_agg256<<<aggGrid, 256, 0, stream>>>(hA, rs, deg, esrc, agg);
    k_gemm_fused<unsigned short><<<gg, 256, 0, stream>>>(agg, hA, w_rel3, w_root3, b_rel3, hB, DD);

    // pooling + head
    hipMemsetAsync(gsum, 0, (size_t)NG * 4, stream);
    hipMemsetAsync(gcnt, 0, (size_t)NG * 4, stream);
    k_pool<<<aggGrid, 256, 0, stream>>>(hB, batch, w_out, gsum, gcnt);
    k_final<<<(NG + 255) / 256, 256, 0, stream>>>(gsum, gcnt, b_out, out);
}

// Round 3
// 1406.983 us; speedup vs baseline: 1.8302x; 1.8302x over previous
//
#include <hip/hip_runtime.h>
#include <math.h>

#define NN 100000   // nodes
#define NE 1600000  // edges
#define NG 2048     // graphs
#define FIN 33      // input features
#define DD 256      // hidden dim

typedef __attribute__((ext_vector_type(8))) short bf16x8;
typedef __attribute__((ext_vector_type(4))) float f32x4;

// ---- bf16 helpers (bit ops, RNE) ----
__device__ __forceinline__ float b2f(unsigned short u){
    union { unsigned int i; float f; } c; c.i = ((unsigned int)u) << 16; return c.f;
}
__device__ __forceinline__ unsigned short f2b(float f){
    union { float f; unsigned int u; } c; c.f = f;
    unsigned int r = c.u + 0x7fffu + ((c.u >> 16) & 1u);   // round-nearest-even
    return (unsigned short)(r >> 16);
}

__device__ __forceinline__ float gelu_tanh(float x){
    float x3 = x * x * x;
    float t = tanhf(0.7978845608028654f * (x + 0.044715f * x3));
    return 0.5f * x * (1.0f + t);
}

// ---------------- CSR build ----------------
__global__ void k_count(const int* __restrict__ dst, int* __restrict__ deg){
    int e = blockIdx.x * 256 + threadIdx.x;
    if(e < NE) atomicAdd(&deg[dst[e]], 1);
}

__global__ void k_scan1(const int* __restrict__ deg, int* __restrict__ rs, int* __restrict__ bsum){
    __shared__ int s[256];
    int t = threadIdx.x, i = blockIdx.x * 256 + t;
    int v = (i < NN) ? deg[i] : 0;
    s[t] = v; __syncthreads();
    for(int off = 1; off < 256; off <<= 1){
        int u = (t >= off) ? s[t - off] : 0;
        __syncthreads();
        s[t] += u;
        __syncthreads();
    }
    if(i < NN) rs[i] = s[t] - v;
    if(t == 255) bsum[blockIdx.x] = s[255];
}

__global__ void k_scan2(int* __restrict__ bsum, int nb){
    __shared__ int s[512];
    int t = threadIdx.x;
    int v = (t < nb) ? bsum[t] : 0;
    s[t] = v; __syncthreads();
    for(int off = 1; off < 512; off <<= 1){
        int u = (t >= off) ? s[t - off] : 0;
        __syncthreads();
        s[t] += u;
        __syncthreads();
    }
    if(t < nb) bsum[t] = s[t] - v;
}

__global__ void k_scan3(int* __restrict__ rs, const int* __restrict__ bsum, int* __restrict__ cursor){
    int i = blockIdx.x * 256 + threadIdx.x;
    if(i < NN){
        int r = rs[i] + bsum[i >> 8];
        rs[i] = r;
        cursor[i] = r;
    }
}

__global__ void k_fill(const int* __restrict__ src, const int* __restrict__ dst,
                       int* __restrict__ cursor, int* __restrict__ esrc){
    int e = blockIdx.x * 256 + threadIdx.x;
    if(e < NE){
        int d = dst[e];
        int p = atomicAdd(&cursor[d], 1);
        esrc[p] = src[e];
    }
}

// ---------------- aggregation (gather via CSR) ----------------
__global__ void k_agg33(const float* __restrict__ x, const int* __restrict__ rs,
                        const int* __restrict__ deg, const int* __restrict__ esrc,
                        float* __restrict__ agg){
    int w = (blockIdx.x * blockDim.x + threadIdx.x) >> 6;
    int lane = threadIdx.x & 63;
    if(w >= NN) return;
    int start = rs[w], cnt = deg[w];
    float acc = 0.f;
    for(int j = 0; j < cnt; j++){
        int s = esrc[start + j];
        if(lane < FIN) acc += x[(size_t)s * FIN + lane];
    }
    if(lane < FIN) agg[(size_t)w * FIN + lane] = acc;
}

__global__ void k_agg256(const unsigned short* __restrict__ h, const int* __restrict__ rs,
                         const int* __restrict__ deg, const int* __restrict__ esrc,
                         unsigned short* __restrict__ agg){
    int w = (blockIdx.x * blockDim.x + threadIdx.x) >> 6;
    int lane = threadIdx.x & 63;
    if(w >= NN) return;
    int start = rs[w], cnt = deg[w];
    float a0 = 0.f, a1 = 0.f, a2 = 0.f, a3 = 0.f;
    const unsigned short* hp = h + lane * 4;
    for(int j = 0; j < cnt; j++){
        int s = esrc[start + j];
        ushort4 v = *(const ushort4*)(hp + (size_t)s * DD);
        a0 += b2f(v.x); a1 += b2f(v.y); a2 += b2f(v.z); a3 += b2f(v.w);
    }
    ushort4 o; o.x = f2b(a0); o.y = f2b(a1); o.z = f2b(a2); o.w = f2b(a3);
    *(ushort4*)(agg + (size_t)w * DD + lane * 4) = o;
}

// ---------------- weight prep: f32 [K][N] -> bf16 transposed [N][K] ----------------
__global__ void k_wt(const float* __restrict__ W, unsigned short* __restrict__ Bt){
    __shared__ float s[16][17];
    int tx = threadIdx.x, ty = threadIdx.y;
    int k = blockIdx.y * 16 + ty;
    int j = blockIdx.x * 16 + tx;
    s[ty][tx] = W[k * DD + j];
    __syncthreads();
    Bt[(size_t)(blockIdx.x * 16 + ty) * DD + blockIdx.y * 16 + tx] = f2b(s[tx][ty]);
}

// ---------------- MFMA dual GEMM + bias + GELU (layers 1-3, K=256+256) ----------------
// out[i][j] = gelu( A0[i,:]@B0[:,j] + A1[i,:]@B1[:,j] + bias[j] ), all [*,256]
// A bf16 row-major; Bt = B^T bf16 [col][k] row-major.
#define BMM 128
#define BNN 128
#define LPAD 40   // LDS row stride in bf16 elems (32 + 8 pad -> 20 words, conflict-free frag reads)

__global__ __launch_bounds__(256) void k_mfma_gemm(
    const unsigned short* __restrict__ A0, const unsigned short* __restrict__ A1,
    const unsigned short* __restrict__ Bt0, const unsigned short* __restrict__ Bt1,
    const float* __restrict__ bias, unsigned short* __restrict__ out)
{
    __shared__ unsigned short As[BMM * LPAD];
    __shared__ unsigned short Bs[BNN * LPAD];

    int t = threadIdx.x;
    int lane = t & 63;
    int w = t >> 6;
    int wm = (w >> 1) * 64;
    int wn = (w & 1) * 64;
    int i0 = blockIdx.x * BMM;
    int j0 = blockIdx.y * BNN;

    f32x4 acc[4][4];
    #pragma unroll
    for(int m = 0; m < 4; m++)
        #pragma unroll
        for(int n = 0; n < 4; n++)
            acc[m][n] = (f32x4){0.f, 0.f, 0.f, 0.f};

    int r16 = lane & 15;
    int kg  = lane >> 4;       // 0..3

    for(int ks = 0; ks < 16; ks++){
        const unsigned short* Ap = (ks < 8) ? A0 : A1;
        const unsigned short* Bp = (ks < 8) ? Bt0 : Bt1;
        int kk = (ks & 7) * 32;

        // stage A,B tiles: 128 rows x 32 k, 16B per thread-slot, 2 passes
        #pragma unroll
        for(int p = 0; p < 2; p++){
            int idx = t + 256 * p;
            int row = idx >> 2;
            int seg = idx & 3;
            int gi = i0 + row;
            bf16x8 va = {};
            if(gi < NN) va = *(const bf16x8*)(Ap + (size_t)gi * DD + kk + seg * 8);
            *(bf16x8*)(As + row * LPAD + seg * 8) = va;
            bf16x8 vb = *(const bf16x8*)(Bp + (size_t)(j0 + row) * DD + kk + seg * 8);
            *(bf16x8*)(Bs + row * LPAD + seg * 8) = vb;
        }
        __syncthreads();

        bf16x8 af[4], bf[4];
        #pragma unroll
        for(int m = 0; m < 4; m++)
            af[m] = *(const bf16x8*)(As + (wm + m * 16 + r16) * LPAD + kg * 8);
        #pragma unroll
        for(int n = 0; n < 4; n++)
            bf[n] = *(const bf16x8*)(Bs + (wn + n * 16 + r16) * LPAD + kg * 8);

        #pragma unroll
        for(int m = 0; m < 4; m++)
            #pragma unroll
            for(int n = 0; n < 4; n++)
                acc[m][n] = __builtin_amdgcn_mfma_f32_16x16x32_bf16(af[m], bf[n], acc[m][n], 0, 0, 0);
        __syncthreads();
    }

    // epilogue: C/D layout col=lane&15, row=(lane>>4)*4+r  [m89-verified]
    int rg = kg * 4;
    #pragma unroll
    for(int n = 0; n < 4; n++){
        int gj = j0 + wn + n * 16 + r16;
        float bb = bias[gj];
        #pragma unroll
        for(int m = 0; m < 4; m++){
            #pragma unroll
            for(int r = 0; r < 4; r++){
                int gi = i0 + wm + m * 16 + rg + r;
                if(gi < NN)
                    out[(size_t)gi * DD + gj] = f2b(gelu_tanh(acc[m][n][r] + bb));
            }
        }
    }
}

// ---------------- VALU fused dual GEMM (layer 0 only, K=33) ----------------
#define BM 64
#define BN 64
#define BKK 16

__global__ __launch_bounds__(256) void k_gemm_fused(
    const float* __restrict__ A0, const float* __restrict__ A1,
    const float* __restrict__ B0, const float* __restrict__ B1,
    const float* __restrict__ bias, unsigned short* __restrict__ out, int K)
{
    __shared__ float As0[BKK][BM + 4];
    __shared__ float As1[BKK][BM + 4];
    __shared__ float Bs0[BKK][BN + 4];
    __shared__ float Bs1[BKK][BN + 4];

    int t  = threadIdx.x;
    int tx = t & 15, ty = t >> 4;
    int i0 = blockIdx.x * BM;
    int j0 = blockIdx.y * BN;

    int am = t >> 2;
    int ak = (t & 3) * 4;
    int bk = t >> 4;
    int bj = (t & 15) * 4;

    float acc[4][4] = {};

    for(int k0 = 0; k0 < K; k0 += BKK){
        #pragma unroll
        for(int q = 0; q < 4; q++){
            int k  = ak + q;
            int gi = i0 + am;
            int gk = k0 + k;
            float v0 = 0.f, v1 = 0.f;
            if(gi < NN && gk < K){
                v0 = A0[(size_t)gi * K + gk];
                v1 = A1[(size_t)gi * K + gk];
            }
            As0[k][am] = v0;
            As1[k][am] = v1;
        }
        {
            int gk = k0 + bk;
            float4 v0 = {0,0,0,0}, v1 = {0,0,0,0};
            if(gk < K){
                v0 = *(const float4*)(B0 + (size_t)gk * DD + j0 + bj);
                v1 = *(const float4*)(B1 + (size_t)gk * DD + j0 + bj);
            }
            *(float4*)&Bs0[bk][bj] = v0;
            *(float4*)&Bs1[bk][bj] = v1;
        }
        __syncthreads();

        #pragma unroll
        for(int k = 0; k < BKK; k++){
            float a0[4], a1[4], b0[4], b1[4];
            #pragma unroll
            for(int m = 0; m < 4; m++){ a0[m] = As0[k][ty*4 + m]; a1[m] = As1[k][ty*4 + m]; }
            #pragma unroll
            for(int n = 0; n < 4; n++){ b0[n] = Bs0[k][tx*4 + n]; b1[n] = Bs1[k][tx*4 + n]; }
            #pragma unroll
            for(int m = 0; m < 4; m++)
                #pragma unroll
                for(int n = 0; n < 4; n++)
                    acc[m][n] += a0[m]*b0[n] + a1[m]*b1[n];
        }
        __syncthreads();
    }

    #pragma unroll
    for(int m = 0; m < 4; m++){
        int gi = i0 + ty*4 + m;
        if(gi >= NN) continue;
        #pragma unroll
        for(int n = 0; n < 4; n++){
            int gj = j0 + tx*4 + n;
            float v = acc[m][n] + bias[gj];
            out[(size_t)gi * DD + gj] = f2b(gelu_tanh(v));
        }
    }
}

// ---------------- pooling + output head ----------------
__global__ void k_pool(const unsigned short* __restrict__ h, const int* __restrict__ batch,
                       const float* __restrict__ wout, float* __restrict__ gsum,
                       int* __restrict__ gcnt){
    int w = (blockIdx.x * blockDim.x + threadIdx.x) >> 6;
    int lane = threadIdx.x & 63;
    if(w >= NN) return;
    ushort4 hv = *(const ushort4*)(h + (size_t)w * DD + lane * 4);
    float4 wv = *(const float4*)(wout + lane * 4);
    float d = b2f(hv.x)*wv.x + b2f(hv.y)*wv.y + b2f(hv.z)*wv.z + b2f(hv.w)*wv.w;
    for(int off = 32; off > 0; off >>= 1) d += __shfl_down(d, off);
    if(lane == 0){
        int g = batch[w];
        atomicAdd(&gsum[g], d);
        atomicAdd(&gcnt[g], 1);
    }
}

__global__ void k_final(const float* __restrict__ gsum, const int* __restrict__ gcnt,
                        const float* __restrict__ bout, float* __restrict__ out){
    int g = blockIdx.x * 256 + threadIdx.x;
    if(g < NG) out[g] = gsum[g] / fmaxf((float)gcnt[g], 1.f) + bout[0];
}

// ---------------- launch ----------------
extern "C" void kernel_launch(void* const* d_in, const int* in_sizes, int n_in,
                              void* d_out, int out_size, void* d_ws, size_t ws_size,
                              hipStream_t stream){
    const float* x       = (const float*)d_in[0];
    const int*   ei      = (const int*)d_in[1];
    const int*   src     = ei;
    const int*   dst     = ei + NE;
    const int*   batch   = (const int*)d_in[2];
    const float* w_rel0  = (const float*)d_in[3];
    const float* b_rel0  = (const float*)d_in[4];
    const float* w_root0 = (const float*)d_in[5];
    const float* w_rel1  = (const float*)d_in[6];
    const float* b_rel1  = (const float*)d_in[7];
    const float* w_root1 = (const float*)d_in[8];
    const float* w_rel2  = (const float*)d_in[9];
    const float* b_rel2  = (const float*)d_in[10];
    const float* w_root2 = (const float*)d_in[11];
    const float* w_rel3  = (const float*)d_in[12];
    const float* b_rel3  = (const float*)d_in[13];
    const float* w_root3 = (const float*)d_in[14];
    const float* w_out   = (const float*)d_in[15];
    const float* b_out   = (const float*)d_in[16];
    float* out = (float*)d_out;

    char* ws = (char*)d_ws;
    size_t off = 0;
    auto alloc = [&](size_t bytes) -> void* {
        void* p = ws + off;
        off = (off + bytes + 255) & ~(size_t)255;
        return p;
    };
    unsigned short* hA  = (unsigned short*)alloc((size_t)NN * DD * 2);
    unsigned short* hB  = (unsigned short*)alloc((size_t)NN * DD * 2);
    unsigned short* agg = (unsigned short*)alloc((size_t)NN * DD * 2);
    int*   deg  = (int*)alloc((size_t)NN * 4);
    int*   rs   = (int*)alloc((size_t)NN * 4);
    int*   cur  = (int*)alloc((size_t)NN * 4);
    int*   esrc = (int*)alloc((size_t)NE * 4);
    int*   bsum = (int*)alloc(512 * 4);
    float* gsum = (float*)alloc((size_t)NG * 4);
    int*   gcnt = (int*)alloc((size_t)NG * 4);
    unsigned short* bt[6];
    for(int i = 0; i < 6; i++) bt[i] = (unsigned short*)alloc((size_t)DD * DD * 2);
    (void)ws_size; (void)in_sizes; (void)n_in; (void)out_size;
    float* aggF = (float*)agg;

    // CSR build
    hipMemsetAsync(deg, 0, (size_t)NN * 4, stream);
    k_count<<<(NE + 255) / 256, 256, 0, stream>>>(dst, deg);
    int nb = (NN + 255) / 256;
    k_scan1<<<nb, 256, 0, stream>>>(deg, rs, bsum);
    k_scan2<<<1, 512, 0, stream>>>(bsum, nb);
    k_scan3<<<nb, 256, 0, stream>>>(rs, bsum, cur);
    k_fill<<<(NE + 255) / 256, 256, 0, stream>>>(src, dst, cur, esrc);

    // weight prep: bf16 transposed copies of the six 256x256 weights
    dim3 wtg(16, 16), wtb(16, 16);
    k_wt<<<wtg, wtb, 0, stream>>>(w_rel1,  bt[0]);
    k_wt<<<wtg, wtb, 0, stream>>>(w_root1, bt[1]);
    k_wt<<<wtg, wtb, 0, stream>>>(w_rel2,  bt[2]);
    k_wt<<<wtg, wtb, 0, stream>>>(w_root2, bt[3]);
    k_wt<<<wtg, wtb, 0, stream>>>(w_rel3,  bt[4]);
    k_wt<<<wtg, wtb, 0, stream>>>(w_root3, bt[5]);

    int aggGrid = (NN + 3) / 4;
    dim3 gg0((NN + BM - 1) / BM, DD / BN);
    dim3 gg1((NN + BMM - 1) / BMM, DD / BNN);

    // layer 0: VALU path, K=33
    k_agg33<<<aggGrid, 256, 0, stream>>>(x, rs, deg, esrc, aggF);
    k_gemm_fused<<<gg0, 256, 0, stream>>>(aggF, x, w_rel0, w_root0, b_rel0, hA, FIN);
    // layers 1..3: MFMA path
    k_agg256<<<aggGrid, 256, 0, stream>>>(hA, rs, deg, esrc, agg);
    k_mfma_gemm<<<gg1, 256, 0, stream>>>(agg, hA, bt[0], bt[1], b_rel1, hB);
    k_agg256<<<aggGrid, 256, 0, stream>>>(hB, rs, deg, esrc, agg);
    k_mfma_gemm<<<gg1, 256, 0, stream>>>(agg, hB, bt[2], bt[3], b_rel2, hA);
    k_agg256<<<aggGrid, 256, 0, stream>>>(hA, rs, deg, esrc, agg);
    k_mfma_gemm<<<gg1, 256, 0, stream>>>(agg, hA, bt[4], bt[5], b_rel3, hB);

    // pooling + head
    hipMemsetAsync(gsum, 0, (size_t)NG * 4, stream);
    hipMemsetAsync(gcnt, 0, (size_t)NG * 4, stream);
    k_pool<<<aggGrid, 256, 0, stream>>>(hB, batch, w_out, gsum, gcnt);
    k_final<<<(NG + 255) / 256, 256, 0, stream>>>(gsum, gcnt, b_out, out);
}

// Round 4
// 1072.030 us; speedup vs baseline: 2.4020x; 1.3124x over previous
//
#include <hip/hip_runtime.h>
#include <math.h>

#define NN 100000   // nodes
#define NE 1600000  // edges
#define NG 2048     // graphs
#define FIN 33      // input features
#define DD 256      // hidden dim

typedef __attribute__((ext_vector_type(8))) short bf16x8;
typedef __attribute__((ext_vector_type(4))) float f32x4;

// ---- bf16 helpers (bit ops, RNE) ----
__device__ __forceinline__ float b2f(unsigned short u){
    union { unsigned int i; float f; } c; c.i = ((unsigned int)u) << 16; return c.f;
}
__device__ __forceinline__ unsigned short f2b(float f){
    union { float f; unsigned int u; } c; c.f = f;
    unsigned int r = c.u + 0x7fffu + ((c.u >> 16) & 1u);   // round-nearest-even
    return (unsigned short)(r >> 16);
}

__device__ __forceinline__ float gelu_tanh(float x){
    float x3 = x * x * x;
    float t = tanhf(0.7978845608028654f * (x + 0.044715f * x3));
    return 0.5f * x * (1.0f + t);
}

// ---------------- CSR build ----------------
__global__ void k_count(const int* __restrict__ dst, int* __restrict__ deg){
    int e = blockIdx.x * 256 + threadIdx.x;
    if(e < NE) atomicAdd(&deg[dst[e]], 1);
}

__global__ void k_scan1(const int* __restrict__ deg, int* __restrict__ rs, int* __restrict__ bsum){
    __shared__ int s[256];
    int t = threadIdx.x, i = blockIdx.x * 256 + t;
    int v = (i < NN) ? deg[i] : 0;
    s[t] = v; __syncthreads();
    for(int off = 1; off < 256; off <<= 1){
        int u = (t >= off) ? s[t - off] : 0;
        __syncthreads();
        s[t] += u;
        __syncthreads();
    }
    if(i < NN) rs[i] = s[t] - v;
    if(t == 255) bsum[blockIdx.x] = s[255];
}

__global__ void k_scan2(int* __restrict__ bsum, int nb){
    __shared__ int s[512];
    int t = threadIdx.x;
    int v = (t < nb) ? bsum[t] : 0;
    s[t] = v; __syncthreads();
    for(int off = 1; off < 512; off <<= 1){
        int u = (t >= off) ? s[t - off] : 0;
        __syncthreads();
        s[t] += u;
        __syncthreads();
    }
    if(t < nb) bsum[t] = s[t] - v;
}

__global__ void k_scan3(int* __restrict__ rs, const int* __restrict__ bsum, int* __restrict__ cursor){
    int i = blockIdx.x * 256 + threadIdx.x;
    if(i < NN){
        int r = rs[i] + bsum[i >> 8];
        rs[i] = r;
        cursor[i] = r;
    }
}

__global__ void k_fill(const int* __restrict__ src, const int* __restrict__ dst,
                       int* __restrict__ cursor, int* __restrict__ esrc){
    int e = blockIdx.x * 256 + threadIdx.x;
    if(e < NE){
        int d = dst[e];
        int p = atomicAdd(&cursor[d], 1);
        esrc[p] = src[e];
    }
}

// ---------------- layer-0 input prep ----------------
// x [NN,33] f32 -> xb [NN,64] bf16, zero-padded k>=33
__global__ void k_xpad(const float* __restrict__ x, unsigned short* __restrict__ xb){
    int idx = blockIdx.x * 256 + threadIdx.x;
    if(idx >= NN * 64) return;
    int n = idx >> 6, c = idx & 63;
    xb[idx] = (c < FIN) ? f2b(x[(size_t)n * FIN + c]) : 0;
}

// gather xb rows: 4 nodes per wave, 16 lanes (128 B) per node, unroll 4
__global__ void k_aggx(const unsigned short* __restrict__ xb, const int* __restrict__ rs,
                       const int* __restrict__ deg, const int* __restrict__ esrc,
                       unsigned short* __restrict__ axb){
    int wv = (blockIdx.x * blockDim.x + threadIdx.x) >> 6;
    int lane = threadIdx.x & 63;
    int node = wv * 4 + (lane >> 4);
    int l16 = lane & 15;
    if(node >= NN) return;
    int start = rs[node], cnt = deg[node];
    float a0 = 0.f, a1 = 0.f, a2 = 0.f, a3 = 0.f;
    const unsigned short* xp = xb + l16 * 4;
    int j = 0;
    for(; j + 4 <= cnt; j += 4){
        int e0 = esrc[start+j], e1 = esrc[start+j+1], e2 = esrc[start+j+2], e3 = esrc[start+j+3];
        ushort4 v0 = *(const ushort4*)(xp + (size_t)e0 * 64);
        ushort4 v1 = *(const ushort4*)(xp + (size_t)e1 * 64);
        ushort4 v2 = *(const ushort4*)(xp + (size_t)e2 * 64);
        ushort4 v3 = *(const ushort4*)(xp + (size_t)e3 * 64);
        a0 += (b2f(v0.x) + b2f(v1.x)) + (b2f(v2.x) + b2f(v3.x));
        a1 += (b2f(v0.y) + b2f(v1.y)) + (b2f(v2.y) + b2f(v3.y));
        a2 += (b2f(v0.z) + b2f(v1.z)) + (b2f(v2.z) + b2f(v3.z));
        a3 += (b2f(v0.w) + b2f(v1.w)) + (b2f(v2.w) + b2f(v3.w));
    }
    for(; j < cnt; j++){
        int e = esrc[start + j];
        ushort4 v = *(const ushort4*)(xp + (size_t)e * 64);
        a0 += b2f(v.x); a1 += b2f(v.y); a2 += b2f(v.z); a3 += b2f(v.w);
    }
    ushort4 o; o.x = f2b(a0); o.y = f2b(a1); o.z = f2b(a2); o.w = f2b(a3);
    *(ushort4*)(axb + (size_t)node * 64 + l16 * 4) = o;
}

// ---------------- aggregation layers 1-3 (gather, unroll 8 for MLP) ----------------
__global__ void k_agg256(const unsigned short* __restrict__ h, const int* __restrict__ rs,
                         const int* __restrict__ deg, const int* __restrict__ esrc,
                         unsigned short* __restrict__ agg){
    int w = (blockIdx.x * blockDim.x + threadIdx.x) >> 6;
    int lane = threadIdx.x & 63;
    if(w >= NN) return;
    int start = rs[w], cnt = deg[w];
    float a0 = 0.f, a1 = 0.f, a2 = 0.f, a3 = 0.f;
    const unsigned short* hp = h + lane * 4;
    int j = 0;
    for(; j + 8 <= cnt; j += 8){
        int e0 = esrc[start+j+0], e1 = esrc[start+j+1], e2 = esrc[start+j+2], e3 = esrc[start+j+3];
        int e4 = esrc[start+j+4], e5 = esrc[start+j+5], e6 = esrc[start+j+6], e7 = esrc[start+j+7];
        ushort4 v0 = *(const ushort4*)(hp + (size_t)e0 * DD);
        ushort4 v1 = *(const ushort4*)(hp + (size_t)e1 * DD);
        ushort4 v2 = *(const ushort4*)(hp + (size_t)e2 * DD);
        ushort4 v3 = *(const ushort4*)(hp + (size_t)e3 * DD);
        ushort4 v4 = *(const ushort4*)(hp + (size_t)e4 * DD);
        ushort4 v5 = *(const ushort4*)(hp + (size_t)e5 * DD);
        ushort4 v6 = *(const ushort4*)(hp + (size_t)e6 * DD);
        ushort4 v7 = *(const ushort4*)(hp + (size_t)e7 * DD);
        a0 += ((b2f(v0.x)+b2f(v1.x)) + (b2f(v2.x)+b2f(v3.x))) + ((b2f(v4.x)+b2f(v5.x)) + (b2f(v6.x)+b2f(v7.x)));
        a1 += ((b2f(v0.y)+b2f(v1.y)) + (b2f(v2.y)+b2f(v3.y))) + ((b2f(v4.y)+b2f(v5.y)) + (b2f(v6.y)+b2f(v7.y)));
        a2 += ((b2f(v0.z)+b2f(v1.z)) + (b2f(v2.z)+b2f(v3.z))) + ((b2f(v4.z)+b2f(v5.z)) + (b2f(v6.z)+b2f(v7.z)));
        a3 += ((b2f(v0.w)+b2f(v1.w)) + (b2f(v2.w)+b2f(v3.w))) + ((b2f(v4.w)+b2f(v5.w)) + (b2f(v6.w)+b2f(v7.w)));
    }
    for(; j < cnt; j++){
        int s = esrc[start + j];
        ushort4 v = *(const ushort4*)(hp + (size_t)s * DD);
        a0 += b2f(v.x); a1 += b2f(v.y); a2 += b2f(v.z); a3 += b2f(v.w);
    }
    ushort4 o; o.x = f2b(a0); o.y = f2b(a1); o.z = f2b(a2); o.w = f2b(a3);
    *(ushort4*)(agg + (size_t)w * DD + lane * 4) = o;
}

// ---------------- weight prep ----------------
// f32 [256][256] -> bf16 transposed [256][256]
__global__ void k_wt(const float* __restrict__ W, unsigned short* __restrict__ Bt){
    __shared__ float s[16][17];
    int tx = threadIdx.x, ty = threadIdx.y;
    int k = blockIdx.y * 16 + ty;
    int j = blockIdx.x * 16 + tx;
    s[ty][tx] = W[k * DD + j];
    __syncthreads();
    Bt[(size_t)(blockIdx.x * 16 + ty) * DD + blockIdx.y * 16 + tx] = f2b(s[tx][ty]);
}

// f32 [33][256] -> bf16 transposed, K padded to 64: Bt[j][k] (zero k>=33)
__global__ void k_wt0(const float* __restrict__ W, unsigned short* __restrict__ Bt){
    int idx = blockIdx.x * 256 + threadIdx.x;
    if(idx >= DD * 64) return;
    int j = idx >> 6, k = idx & 63;
    Bt[idx] = (k < FIN) ? f2b(W[(size_t)k * DD + j]) : 0;
}

// ---------------- MFMA dual GEMM + bias + GELU ----------------
// out[i][j] = gelu( A0[i,:]@B0 + A1[i,:]@B1 + bias[j] )  -> bf16 [NN,256]
// A row-major [NN, AST] bf16; Bt row-major [256, AST] bf16 (= B^T).
// KS = K-steps (of 32) per matrix; AST = A/B row stride.
#define BMM 128
#define BNN 128
#define LPAD 40   // LDS row stride in bf16 (32 + 8 pad)

template<int KS, int AST>
__global__ __launch_bounds__(256) void k_mfma_gemm(
    const unsigned short* __restrict__ A0, const unsigned short* __restrict__ A1,
    const unsigned short* __restrict__ Bt0, const unsigned short* __restrict__ Bt1,
    const float* __restrict__ bias, unsigned short* __restrict__ out)
{
    __shared__ unsigned short As[BMM * LPAD];
    __shared__ unsigned short Bs[BNN * LPAD];

    int t = threadIdx.x;
    int lane = t & 63;
    int w = t >> 6;
    int wm = (w >> 1) * 64;
    int wn = (w & 1) * 64;
    int i0 = blockIdx.x * BMM;
    int j0 = blockIdx.y * BNN;

    f32x4 acc[4][4];
    #pragma unroll
    for(int m = 0; m < 4; m++)
        #pragma unroll
        for(int n = 0; n < 4; n++)
            acc[m][n] = (f32x4){0.f, 0.f, 0.f, 0.f};

    int r16 = lane & 15;
    int kg  = lane >> 4;

    for(int ks = 0; ks < 2 * KS; ks++){
        const unsigned short* Ap = (ks < KS) ? A0 : A1;
        const unsigned short* Bp = (ks < KS) ? Bt0 : Bt1;
        int kk = (ks < KS ? ks : ks - KS) * 32;

        #pragma unroll
        for(int p = 0; p < 2; p++){
            int idx = t + 256 * p;
            int row = idx >> 2;
            int seg = idx & 3;
            int gi = i0 + row;
            bf16x8 va = {};
            if(gi < NN) va = *(const bf16x8*)(Ap + (size_t)gi * AST + kk + seg * 8);
            *(bf16x8*)(As + row * LPAD + seg * 8) = va;
            bf16x8 vb = *(const bf16x8*)(Bp + (size_t)(j0 + row) * AST + kk + seg * 8);
            *(bf16x8*)(Bs + row * LPAD + seg * 8) = vb;
        }
        __syncthreads();

        bf16x8 af[4], bfr[4];
        #pragma unroll
        for(int m = 0; m < 4; m++)
            af[m] = *(const bf16x8*)(As + (wm + m * 16 + r16) * LPAD + kg * 8);
        #pragma unroll
        for(int n = 0; n < 4; n++)
            bfr[n] = *(const bf16x8*)(Bs + (wn + n * 16 + r16) * LPAD + kg * 8);

        #pragma unroll
        for(int m = 0; m < 4; m++)
            #pragma unroll
            for(int n = 0; n < 4; n++)
                acc[m][n] = __builtin_amdgcn_mfma_f32_16x16x32_bf16(af[m], bfr[n], acc[m][n], 0, 0, 0);
        __syncthreads();
    }

    // C/D layout: col=lane&15, row=(lane>>4)*4+r  [m89-verified]
    int rg = kg * 4;
    #pragma unroll
    for(int n = 0; n < 4; n++){
        int gj = j0 + wn + n * 16 + r16;
        float bb = bias[gj];
        #pragma unroll
        for(int m = 0; m < 4; m++){
            #pragma unroll
            for(int r = 0; r < 4; r++){
                int gi = i0 + wm + m * 16 + rg + r;
                if(gi < NN)
                    out[(size_t)gi * DD + gj] = f2b(gelu_tanh(acc[m][n][r] + bb));
            }
        }
    }
}

// ---------------- pooling + output head ----------------
__global__ void k_pool(const unsigned short* __restrict__ h, const int* __restrict__ batch,
                       const float* __restrict__ wout, float* __restrict__ gsum,
                       int* __restrict__ gcnt){
    int w = (blockIdx.x * blockDim.x + threadIdx.x) >> 6;
    int lane = threadIdx.x & 63;
    if(w >= NN) return;
    ushort4 hv = *(const ushort4*)(h + (size_t)w * DD + lane * 4);
    float4 wv = *(const float4*)(wout + lane * 4);
    float d = b2f(hv.x)*wv.x + b2f(hv.y)*wv.y + b2f(hv.z)*wv.z + b2f(hv.w)*wv.w;
    for(int off = 32; off > 0; off >>= 1) d += __shfl_down(d, off);
    if(lane == 0){
        int g = batch[w];
        atomicAdd(&gsum[g], d);
        atomicAdd(&gcnt[g], 1);
    }
}

__global__ void k_final(const float* __restrict__ gsum, const int* __restrict__ gcnt,
                        const float* __restrict__ bout, float* __restrict__ out){
    int g = blockIdx.x * 256 + threadIdx.x;
    if(g < NG) out[g] = gsum[g] / fmaxf((float)gcnt[g], 1.f) + bout[0];
}

// ---------------- launch ----------------
extern "C" void kernel_launch(void* const* d_in, const int* in_sizes, int n_in,
                              void* d_out, int out_size, void* d_ws, size_t ws_size,
                              hipStream_t stream){
    const float* x       = (const float*)d_in[0];
    const int*   ei      = (const int*)d_in[1];
    const int*   src     = ei;
    const int*   dst     = ei + NE;
    const int*   batch   = (const int*)d_in[2];
    const float* w_rel0  = (const float*)d_in[3];
    const float* b_rel0  = (const float*)d_in[4];
    const float* w_root0 = (const float*)d_in[5];
    const float* w_rel1  = (const float*)d_in[6];
    const float* b_rel1  = (const float*)d_in[7];
    const float* w_root1 = (const float*)d_in[8];
    const float* w_rel2  = (const float*)d_in[9];
    const float* b_rel2  = (const float*)d_in[10];
    const float* w_root2 = (const float*)d_in[11];
    const float* w_rel3  = (const float*)d_in[12];
    const float* b_rel3  = (const float*)d_in[13];
    const float* w_root3 = (const float*)d_in[14];
    const float* w_out   = (const float*)d_in[15];
    const float* b_out   = (const float*)d_in[16];
    float* out = (float*)d_out;

    char* ws = (char*)d_ws;
    size_t off = 0;
    auto alloc = [&](size_t bytes) -> void* {
        void* p = ws + off;
        off = (off + bytes + 255) & ~(size_t)255;
        return p;
    };
    unsigned short* hA  = (unsigned short*)alloc((size_t)NN * DD * 2);  // 51.2 MB
    unsigned short* hB  = (unsigned short*)alloc((size_t)NN * DD * 2);  // 51.2 MB
    unsigned short* agg = (unsigned short*)alloc((size_t)NN * DD * 2);  // 51.2 MB
    int*   deg  = (int*)alloc((size_t)NN * 4);
    int*   rs   = (int*)alloc((size_t)NN * 4);
    int*   cur  = (int*)alloc((size_t)NN * 4);
    int*   esrc = (int*)alloc((size_t)NE * 4);
    int*   bsum = (int*)alloc(512 * 4);
    float* gsum = (float*)alloc((size_t)NG * 4);
    int*   gcnt = (int*)alloc((size_t)NG * 4);
    unsigned short* bt[6];
    for(int i = 0; i < 6; i++) bt[i] = (unsigned short*)alloc((size_t)DD * DD * 2);
    unsigned short* bt0r = (unsigned short*)alloc((size_t)DD * 64 * 2);
    unsigned short* bt0o = (unsigned short*)alloc((size_t)DD * 64 * 2);
    (void)ws_size; (void)in_sizes; (void)n_in; (void)out_size;

    // layer-0 staging lives inside the (otherwise idle) agg buffer
    unsigned short* xb  = agg;                              // [NN,64] bf16 = 12.8 MB
    unsigned short* axb = agg + (size_t)NN * 64 + 128;      // [NN,64] bf16 = 12.8 MB

    // CSR build
    hipMemsetAsync(deg, 0, (size_t)NN * 4, stream);
    k_count<<<(NE + 255) / 256, 256, 0, stream>>>(dst, deg);
    int nb = (NN + 255) / 256;
    k_scan1<<<nb, 256, 0, stream>>>(deg, rs, bsum);
    k_scan2<<<1, 512, 0, stream>>>(bsum, nb);
    k_scan3<<<nb, 256, 0, stream>>>(rs, bsum, cur);
    k_fill<<<(NE + 255) / 256, 256, 0, stream>>>(src, dst, cur, esrc);

    // weight prep
    dim3 wtg(16, 16), wtb(16, 16);
    k_wt<<<wtg, wtb, 0, stream>>>(w_rel1,  bt[0]);
    k_wt<<<wtg, wtb, 0, stream>>>(w_root1, bt[1]);
    k_wt<<<wtg, wtb, 0, stream>>>(w_rel2,  bt[2]);
    k_wt<<<wtg, wtb, 0, stream>>>(w_root2, bt[3]);
    k_wt<<<wtg, wtb, 0, stream>>>(w_rel3,  bt[4]);
    k_wt<<<wtg, wtb, 0, stream>>>(w_root3, bt[5]);
    k_wt0<<<(DD * 64 + 255) / 256, 256, 0, stream>>>(w_rel0,  bt0r);
    k_wt0<<<(DD * 64 + 255) / 256, 256, 0, stream>>>(w_root0, bt0o);
    k_xpad<<<(NN * 64 + 255) / 256, 256, 0, stream>>>(x, xb);

    int aggGrid = (NN + 3) / 4;          // one wave per node, 4 waves/block
    int aggxGrid = (NN + 15) / 16;       // 4 nodes per wave
    dim3 gg((NN + BMM - 1) / BMM, DD / BNN);

    // layer 0: bf16 gather (128 B rows) + MFMA K=64
    k_aggx<<<aggxGrid, 256, 0, stream>>>(xb, rs, deg, esrc, axb);
    k_mfma_gemm<2, 64><<<gg, 256, 0, stream>>>(axb, xb, bt0r, bt0o, b_rel0, hA);
    // layers 1..3
    k_agg256<<<aggGrid, 256, 0, stream>>>(hA, rs, deg, esrc, agg);
    k_mfma_gemm<8, 256><<<gg, 256, 0, stream>>>(agg, hA, bt[0], bt[1], b_rel1, hB);
    k_agg256<<<aggGrid, 256, 0, stream>>>(hB, rs, deg, esrc, agg);
    k_mfma_gemm<8, 256><<<gg, 256, 0, stream>>>(agg, hB, bt[2], bt[3], b_rel2, hA);
    k_agg256<<<aggGrid, 256, 0, stream>>>(hA, rs, deg, esrc, agg);
    k_mfma_gemm<8, 256><<<gg, 256, 0, stream>>>(agg, hA, bt[4], bt[5], b_rel3, hB);

    // pooling + head
    hipMemsetAsync(gsum, 0, (size_t)NG * 4, stream);
    hipMemsetAsync(gcnt, 0, (size_t)NG * 4, stream);
    k_pool<<<aggGrid, 256, 0, stream>>>(hB, batch, w_out, gsum, gcnt);
    k_final<<<(NG + 255) / 256, 256, 0, stream>>>(gsum, gcnt, b_out, out);
}

// Round 5
// 891.593 us; speedup vs baseline: 2.8881x; 1.2024x over previous
//
#include <hip/hip_runtime.h>
#include <math.h>

#define NN 100000   // nodes
#define NE 1600000  // edges
#define NG 2048     // graphs
#define FIN 33      // input features
#define DD 256      // hidden dim

// binning constants
#define SH 8                      // bucket = dst >> 8 (256 nodes/bucket)
#define NB ((NN + 255) >> 8)      // 391 buckets
#define CH 4096                   // edges per k_bin block
#define PCAP 4608                 // per-bucket pair capacity (mean 4092 + 8 sigma)
#define ESCAP 6144                // k_bcsr LDS esrc stage capacity

typedef __attribute__((ext_vector_type(8))) short bf16x8;
typedef __attribute__((ext_vector_type(4))) float f32x4;

// ---- bf16 helpers (bit ops, RNE) ----
__device__ __forceinline__ float b2f(unsigned short u){
    union { unsigned int i; float f; } c; c.i = ((unsigned int)u) << 16; return c.f;
}
__device__ __forceinline__ unsigned short f2b(float f){
    union { float f; unsigned int u; } c; c.f = f;
    unsigned int r = c.u + 0x7fffu + ((c.u >> 16) & 1u);
    return (unsigned short)(r >> 16);
}

__device__ __forceinline__ float gelu_tanh(float x){
    float x3 = x * x * x;
    float t = tanhf(0.7978845608028654f * (x + 0.044715f * x3));
    return 0.5f * x * (1.0f + t);
}

// ---------------- CSR build via LDS-staged binning ----------------
// pass 1: block-local counting sort by bucket, per-bucket range reservation,
// coalesced flush into padded per-bucket regions of `pairs`.
__global__ __launch_bounds__(256) void k_bin(const int* __restrict__ src,
                                             const int* __restrict__ dst,
                                             int* __restrict__ gcur,
                                             int2* __restrict__ pairs){
    __shared__ int cnt[NB];
    __shared__ int lb[NB];
    __shared__ int gbase[NB];
    __shared__ int sc[512];
    __shared__ int2 stage[CH];

    int t = threadIdx.x;
    for(int i = t; i < NB; i += 256) cnt[i] = 0;
    __syncthreads();

    int e0 = blockIdx.x * CH;
    int n = NE - e0; if(n > CH) n = CH;

    int  myb[16];
    int  myr[16];
    int2 myp[16];
    #pragma unroll
    for(int k = 0; k < 16; k++){
        int e = e0 + t + k * 256;
        if(e < NE){
            int s = src[e], d = dst[e];
            int b = d >> SH;
            myr[k] = atomicAdd(&cnt[b], 1);
            myb[k] = b;
            myp[k] = make_int2(s, d);
        } else myb[k] = -1;
    }
    __syncthreads();

    // inclusive Hillis-Steele over 512 slots (2 per thread)
    sc[t]       = (t       < NB) ? cnt[t]       : 0;
    sc[t + 256] = (t + 256 < NB) ? cnt[t + 256] : 0;
    __syncthreads();
    for(int off = 1; off < 512; off <<= 1){
        int a  = (t >= off)       ? sc[t - off]       : 0;
        int b2 = (t + 256 >= off) ? sc[t + 256 - off] : 0;
        __syncthreads();
        sc[t] += a; sc[t + 256] += b2;
        __syncthreads();
    }
    for(int i = t; i < NB; i += 256){
        lb[i] = sc[i] - cnt[i];
        int c = cnt[i];
        gbase[i] = (c > 0) ? atomicAdd(&gcur[i], c) : 0;
    }
    __syncthreads();

    // scatter into LDS stage (sorted by bucket)
    #pragma unroll
    for(int k = 0; k < 16; k++){
        if(myb[k] >= 0) stage[lb[myb[k]] + myr[k]] = myp[k];
    }
    __syncthreads();

    // coalesced-run flush into padded per-bucket regions
    for(int i = t; i < n; i += 256){
        int2 p = stage[i];
        int b = p.y >> SH;
        int tgt = gbase[b] + (i - lb[b]);
        if(tgt < PCAP) pairs[(size_t)b * PCAP + tgt] = p;
    }
}

// pass 2: exclusive scan of per-bucket counts -> boff
__global__ void k_sscan(const int* __restrict__ gcur, int* __restrict__ boff){
    __shared__ int s[512];
    int t = threadIdx.x;
    int v = 0;
    if(t < NB){ v = gcur[t]; if(v > PCAP) v = PCAP; }
    s[t] = v; __syncthreads();
    for(int off = 1; off < 512; off <<= 1){
        int u = (t >= off) ? s[t - off] : 0;
        __syncthreads();
        s[t] += u;
        __syncthreads();
    }
    if(t < NB) boff[t] = s[t] - v;
}

// pass 3: per-bucket local CSR in LDS, coalesced esrc/deg/rs writes
__global__ __launch_bounds__(256) void k_bcsr(const int2* __restrict__ pairs,
                                              const int* __restrict__ gcur,
                                              const int* __restrict__ boff,
                                              int* __restrict__ deg,
                                              int* __restrict__ rs,
                                              int* __restrict__ esrc){
    __shared__ int hist[256];
    __shared__ int sc[256];
    __shared__ int cur2[256];
    __shared__ int est[ESCAP];

    int b = blockIdx.x;
    int t = threadIdx.x;
    int m = gcur[b]; if(m > PCAP) m = PCAP;
    int pstart = boff[b];
    const int2* bp = pairs + (size_t)b * PCAP;

    hist[t] = 0;
    __syncthreads();
    for(int i = t; i < m; i += 256) atomicAdd(&hist[bp[i].y & 255], 1);
    __syncthreads();

    // inclusive scan over 256
    sc[t] = hist[t]; __syncthreads();
    for(int off = 1; off < 256; off <<= 1){
        int u = (t >= off) ? sc[t - off] : 0;
        __syncthreads();
        sc[t] += u;
        __syncthreads();
    }
    int excl = sc[t] - hist[t];
    cur2[t] = excl;
    int node = (b << 8) + t;
    if(node < NN){
        deg[node] = hist[t];
        rs[node]  = pstart + excl;
    }
    __syncthreads();

    for(int i = t; i < m; i += 256){
        int2 p = bp[i];
        int pos = atomicAdd(&cur2[p.y & 255], 1);
        if(pos < ESCAP) est[pos] = p.x;
        else esrc[pstart + pos] = p.x;   // astronomically rare fallback
    }
    __syncthreads();
    int lim = (m < ESCAP) ? m : ESCAP;
    for(int i = t; i < lim; i += 256) esrc[pstart + i] = est[i];
}

// ---------------- layer-0 input prep ----------------
__global__ void k_xpad(const float* __restrict__ x, unsigned short* __restrict__ xb){
    int idx = blockIdx.x * 256 + threadIdx.x;
    if(idx >= NN * 64) return;
    int n = idx >> 6, c = idx & 63;
    xb[idx] = (c < FIN) ? f2b(x[(size_t)n * FIN + c]) : 0;
}

__global__ void k_aggx(const unsigned short* __restrict__ xb, const int* __restrict__ rs,
                       const int* __restrict__ deg, const int* __restrict__ esrc,
                       unsigned short* __restrict__ axb){
    int wv = (blockIdx.x * blockDim.x + threadIdx.x) >> 6;
    int lane = threadIdx.x & 63;
    int node = wv * 4 + (lane >> 4);
    int l16 = lane & 15;
    if(node >= NN) return;
    int start = rs[node], cnt = deg[node];
    float a0 = 0.f, a1 = 0.f, a2 = 0.f, a3 = 0.f;
    const unsigned short* xp = xb + l16 * 4;
    int j = 0;
    for(; j + 4 <= cnt; j += 4){
        int e0 = esrc[start+j], e1 = esrc[start+j+1], e2 = esrc[start+j+2], e3 = esrc[start+j+3];
        ushort4 v0 = *(const ushort4*)(xp + (size_t)e0 * 64);
        ushort4 v1 = *(const ushort4*)(xp + (size_t)e1 * 64);
        ushort4 v2 = *(const ushort4*)(xp + (size_t)e2 * 64);
        ushort4 v3 = *(const ushort4*)(xp + (size_t)e3 * 64);
        a0 += (b2f(v0.x) + b2f(v1.x)) + (b2f(v2.x) + b2f(v3.x));
        a1 += (b2f(v0.y) + b2f(v1.y)) + (b2f(v2.y) + b2f(v3.y));
        a2 += (b2f(v0.z) + b2f(v1.z)) + (b2f(v2.z) + b2f(v3.z));
        a3 += (b2f(v0.w) + b2f(v1.w)) + (b2f(v2.w) + b2f(v3.w));
    }
    for(; j < cnt; j++){
        int e = esrc[start + j];
        ushort4 v = *(const ushort4*)(xp + (size_t)e * 64);
        a0 += b2f(v.x); a1 += b2f(v.y); a2 += b2f(v.z); a3 += b2f(v.w);
    }
    ushort4 o; o.x = f2b(a0); o.y = f2b(a1); o.z = f2b(a2); o.w = f2b(a3);
    *(ushort4*)(axb + (size_t)node * 64 + l16 * 4) = o;
}

// ---------------- aggregation layers 1-3 ----------------
__global__ void k_agg256(const unsigned short* __restrict__ h, const int* __restrict__ rs,
                         const int* __restrict__ deg, const int* __restrict__ esrc,
                         unsigned short* __restrict__ agg){
    int w = (blockIdx.x * blockDim.x + threadIdx.x) >> 6;
    int lane = threadIdx.x & 63;
    if(w >= NN) return;
    int start = rs[w], cnt = deg[w];
    float a0 = 0.f, a1 = 0.f, a2 = 0.f, a3 = 0.f;
    const unsigned short* hp = h + lane * 4;
    int j = 0;
    for(; j + 8 <= cnt; j += 8){
        int e0 = esrc[start+j+0], e1 = esrc[start+j+1], e2 = esrc[start+j+2], e3 = esrc[start+j+3];
        int e4 = esrc[start+j+4], e5 = esrc[start+j+5], e6 = esrc[start+j+6], e7 = esrc[start+j+7];
        ushort4 v0 = *(const ushort4*)(hp + (size_t)e0 * DD);
        ushort4 v1 = *(const ushort4*)(hp + (size_t)e1 * DD);
        ushort4 v2 = *(const ushort4*)(hp + (size_t)e2 * DD);
        ushort4 v3 = *(const ushort4*)(hp + (size_t)e3 * DD);
        ushort4 v4 = *(const ushort4*)(hp + (size_t)e4 * DD);
        ushort4 v5 = *(const ushort4*)(hp + (size_t)e5 * DD);
        ushort4 v6 = *(const ushort4*)(hp + (size_t)e6 * DD);
        ushort4 v7 = *(const ushort4*)(hp + (size_t)e7 * DD);
        a0 += ((b2f(v0.x)+b2f(v1.x)) + (b2f(v2.x)+b2f(v3.x))) + ((b2f(v4.x)+b2f(v5.x)) + (b2f(v6.x)+b2f(v7.x)));
        a1 += ((b2f(v0.y)+b2f(v1.y)) + (b2f(v2.y)+b2f(v3.y))) + ((b2f(v4.y)+b2f(v5.y)) + (b2f(v6.y)+b2f(v7.y)));
        a2 += ((b2f(v0.z)+b2f(v1.z)) + (b2f(v2.z)+b2f(v3.z))) + ((b2f(v4.z)+b2f(v5.z)) + (b2f(v6.z)+b2f(v7.z)));
        a3 += ((b2f(v0.w)+b2f(v1.w)) + (b2f(v2.w)+b2f(v3.w))) + ((b2f(v4.w)+b2f(v5.w)) + (b2f(v6.w)+b2f(v7.w)));
    }
    for(; j < cnt; j++){
        int s = esrc[start + j];
        ushort4 v = *(const ushort4*)(hp + (size_t)s * DD);
        a0 += b2f(v.x); a1 += b2f(v.y); a2 += b2f(v.z); a3 += b2f(v.w);
    }
    ushort4 o; o.x = f2b(a0); o.y = f2b(a1); o.z = f2b(a2); o.w = f2b(a3);
    *(ushort4*)(agg + (size_t)w * DD + lane * 4) = o;
}

// ---------------- weight prep ----------------
__global__ void k_wt(const float* __restrict__ W, unsigned short* __restrict__ Bt){
    __shared__ float s[16][17];
    int tx = threadIdx.x, ty = threadIdx.y;
    int k = blockIdx.y * 16 + ty;
    int j = blockIdx.x * 16 + tx;
    s[ty][tx] = W[k * DD + j];
    __syncthreads();
    Bt[(size_t)(blockIdx.x * 16 + ty) * DD + blockIdx.y * 16 + tx] = f2b(s[tx][ty]);
}

__global__ void k_wt0(const float* __restrict__ W, unsigned short* __restrict__ Bt){
    int idx = blockIdx.x * 256 + threadIdx.x;
    if(idx >= DD * 64) return;
    int j = idx >> 6, k = idx & 63;
    Bt[idx] = (k < FIN) ? f2b(W[(size_t)k * DD + j]) : 0;
}

// ---------------- MFMA dual GEMM + bias + GELU (64-k per barrier pair) ----------------
#define BMM 128
#define BNN 128
#define LPAD 40

template<int KS, int AST>   // KS = steps-of-32 per matrix (even); AST = row stride
__global__ __launch_bounds__(256) void k_mfma_gemm(
    const unsigned short* __restrict__ A0, const unsigned short* __restrict__ A1,
    const unsigned short* __restrict__ Bt0, const unsigned short* __restrict__ Bt1,
    const float* __restrict__ bias, unsigned short* __restrict__ out)
{
    __shared__ unsigned short As[2][BMM * LPAD];
    __shared__ unsigned short Bs[2][BNN * LPAD];

    int t = threadIdx.x;
    int lane = t & 63;
    int w = t >> 6;
    int wm = (w >> 1) * 64;
    int wn = (w & 1) * 64;
    int i0 = blockIdx.x * BMM;
    int j0 = blockIdx.y * BNN;

    f32x4 acc[4][4];
    #pragma unroll
    for(int m = 0; m < 4; m++)
        #pragma unroll
        for(int n = 0; n < 4; n++)
            acc[m][n] = (f32x4){0.f, 0.f, 0.f, 0.f};

    int r16 = lane & 15;
    int kg  = lane >> 4;

    for(int os = 0; os < KS; os++){          // each outer step covers 64 k
        const unsigned short* Ap = (os < KS/2) ? A0 : A1;
        const unsigned short* Bp = (os < KS/2) ? Bt0 : Bt1;
        int kb = ((os < KS/2) ? os : os - KS/2) * 64;

        #pragma unroll
        for(int h = 0; h < 2; h++){
            int kk = kb + h * 32;
            #pragma unroll
            for(int p = 0; p < 2; p++){
                int idx = t + 256 * p;
                int row = idx >> 2;
                int seg = idx & 3;
                int gi = i0 + row;
                bf16x8 va = {};
                if(gi < NN) va = *(const bf16x8*)(Ap + (size_t)gi * AST + kk + seg * 8);
                *(bf16x8*)(&As[h][row * LPAD + seg * 8]) = va;
                bf16x8 vb = *(const bf16x8*)(Bp + (size_t)(j0 + row) * AST + kk + seg * 8);
                *(bf16x8*)(&Bs[h][row * LPAD + seg * 8]) = vb;
            }
        }
        __syncthreads();

        #pragma unroll
        for(int h = 0; h < 2; h++){
            bf16x8 af[4], bfr[4];
            #pragma unroll
            for(int m = 0; m < 4; m++)
                af[m] = *(const bf16x8*)(&As[h][(wm + m * 16 + r16) * LPAD + kg * 8]);
            #pragma unroll
            for(int n = 0; n < 4; n++)
                bfr[n] = *(const bf16x8*)(&Bs[h][(wn + n * 16 + r16) * LPAD + kg * 8]);
            #pragma unroll
            for(int m = 0; m < 4; m++)
                #pragma unroll
                for(int n = 0; n < 4; n++)
                    acc[m][n] = __builtin_amdgcn_mfma_f32_16x16x32_bf16(af[m], bfr[n], acc[m][n], 0, 0, 0);
        }
        __syncthreads();
    }

    // C/D layout: col=lane&15, row=(lane>>4)*4+r  [m89-verified]
    int rg = kg * 4;
    #pragma unroll
    for(int n = 0; n < 4; n++){
        int gj = j0 + wn + n * 16 + r16;
        float bb = bias[gj];
        #pragma unroll
        for(int m = 0; m < 4; m++){
            #pragma unroll
            for(int r = 0; r < 4; r++){
                int gi = i0 + wm + m * 16 + rg + r;
                if(gi < NN)
                    out[(size_t)gi * DD + gj] = f2b(gelu_tanh(acc[m][n][r] + bb));
            }
        }
    }
}

// ---------------- pooling + output head ----------------
__global__ void k_pool(const unsigned short* __restrict__ h, const int* __restrict__ batch,
                       const float* __restrict__ wout, float* __restrict__ gsum,
                       int* __restrict__ gcnt){
    int w = (blockIdx.x * blockDim.x + threadIdx.x) >> 6;
    int lane = threadIdx.x & 63;
    if(w >= NN) return;
    ushort4 hv = *(const ushort4*)(h + (size_t)w * DD + lane * 4);
    float4 wv = *(const float4*)(wout + lane * 4);
    float d = b2f(hv.x)*wv.x + b2f(hv.y)*wv.y + b2f(hv.z)*wv.z + b2f(hv.w)*wv.w;
    for(int off = 32; off > 0; off >>= 1) d += __shfl_down(d, off);
    if(lane == 0){
        int g = batch[w];
        atomicAdd(&gsum[g], d);
        atomicAdd(&gcnt[g], 1);
    }
}

__global__ void k_final(const float* __restrict__ gsum, const int* __restrict__ gcnt,
                        const float* __restrict__ bout, float* __restrict__ out){
    int g = blockIdx.x * 256 + threadIdx.x;
    if(g < NG) out[g] = gsum[g] / fmaxf((float)gcnt[g], 1.f) + bout[0];
}

// ---------------- launch ----------------
extern "C" void kernel_launch(void* const* d_in, const int* in_sizes, int n_in,
                              void* d_out, int out_size, void* d_ws, size_t ws_size,
                              hipStream_t stream){
    const float* x       = (const float*)d_in[0];
    const int*   ei      = (const int*)d_in[1];
    const int*   src     = ei;
    const int*   dst     = ei + NE;
    const int*   batch   = (const int*)d_in[2];
    const float* w_rel0  = (const float*)d_in[3];
    const float* b_rel0  = (const float*)d_in[4];
    const float* w_root0 = (const float*)d_in[5];
    const float* w_rel1  = (const float*)d_in[6];
    const float* b_rel1  = (const float*)d_in[7];
    const float* w_root1 = (const float*)d_in[8];
    const float* w_rel2  = (const float*)d_in[9];
    const float* b_rel2  = (const float*)d_in[10];
    const float* w_root2 = (const float*)d_in[11];
    const float* w_rel3  = (const float*)d_in[12];
    const float* b_rel3  = (const float*)d_in[13];
    const float* w_root3 = (const float*)d_in[14];
    const float* w_out   = (const float*)d_in[15];
    const float* b_out   = (const float*)d_in[16];
    float* out = (float*)d_out;

    char* ws = (char*)d_ws;
    size_t off = 0;
    auto alloc = [&](size_t bytes) -> void* {
        void* p = ws + off;
        off = (off + bytes + 255) & ~(size_t)255;
        return p;
    };
    unsigned short* hA  = (unsigned short*)alloc((size_t)NN * DD * 2);  // 51.2 MB
    unsigned short* hB  = (unsigned short*)alloc((size_t)NN * DD * 2);  // 51.2 MB
    unsigned short* agg = (unsigned short*)alloc((size_t)NN * DD * 2);  // 51.2 MB
    int*   deg  = (int*)alloc((size_t)NN * 4);
    int*   rs   = (int*)alloc((size_t)NN * 4);
    int*   esrc = (int*)alloc((size_t)NE * 4);
    int*   gcur = (int*)alloc(512 * 4);
    int*   boff = (int*)alloc(512 * 4);
    float* gsum = (float*)alloc((size_t)NG * 4);
    int*   gcnt = (int*)alloc((size_t)NG * 4);
    unsigned short* bt[6];
    for(int i = 0; i < 6; i++) bt[i] = (unsigned short*)alloc((size_t)DD * DD * 2);
    unsigned short* bt0r = (unsigned short*)alloc((size_t)DD * 64 * 2);
    unsigned short* bt0o = (unsigned short*)alloc((size_t)DD * 64 * 2);
    (void)ws_size; (void)in_sizes; (void)n_in; (void)out_size;

    // transient overlays (dead before their hosts are written):
    int2* pairs = (int2*)hB;                                // 14.4 MB, used only in CSR build
    unsigned short* xb  = agg;                              // [NN,64] bf16
    unsigned short* axb = agg + (size_t)NN * 64 + 128;      // [NN,64] bf16

    // CSR build via binning
    hipMemsetAsync(gcur, 0, 512 * 4, stream);
    k_bin<<<(NE + CH - 1) / CH, 256, 0, stream>>>(src, dst, gcur, pairs);
    k_sscan<<<1, 512, 0, stream>>>(gcur, boff);
    k_bcsr<<<NB, 256, 0, stream>>>(pairs, gcur, boff, deg, rs, esrc);

    // weight prep
    dim3 wtg(16, 16), wtb(16, 16);
    k_wt<<<wtg, wtb, 0, stream>>>(w_rel1,  bt[0]);
    k_wt<<<wtg, wtb, 0, stream>>>(w_root1, bt[1]);
    k_wt<<<wtg, wtb, 0, stream>>>(w_rel2,  bt[2]);
    k_wt<<<wtg, wtb, 0, stream>>>(w_root2, bt[3]);
    k_wt<<<wtg, wtb, 0, stream>>>(w_rel3,  bt[4]);
    k_wt<<<wtg, wtb, 0, stream>>>(w_root3, bt[5]);
    k_wt0<<<(DD * 64 + 255) / 256, 256, 0, stream>>>(w_rel0,  bt0r);
    k_wt0<<<(DD * 64 + 255) / 256, 256, 0, stream>>>(w_root0, bt0o);
    k_xpad<<<(NN * 64 + 255) / 256, 256, 0, stream>>>(x, xb);

    int aggGrid = (NN + 3) / 4;
    int aggxGrid = (NN + 15) / 16;
    dim3 gg((NN + BMM - 1) / BMM, DD / BNN);

    // layer 0
    k_aggx<<<aggxGrid, 256, 0, stream>>>(xb, rs, deg, esrc, axb);
    k_mfma_gemm<2, 64><<<gg, 256, 0, stream>>>(axb, xb, bt0r, bt0o, b_rel0, hA);
    // layers 1..3
    k_agg256<<<aggGrid, 256, 0, stream>>>(hA, rs, deg, esrc, agg);
    k_mfma_gemm<8, 256><<<gg, 256, 0, stream>>>(agg, hA, bt[0], bt[1], b_rel1, hB);
    k_agg256<<<aggGrid, 256, 0, stream>>>(hB, rs, deg, esrc, agg);
    k_mfma_gemm<8, 256><<<gg, 256, 0, stream>>>(agg, hB, bt[2], bt[3], b_rel2, hA);
    k_agg256<<<aggGrid, 256, 0, stream>>>(hA, rs, deg, esrc, agg);
    k_mfma_gemm<8, 256><<<gg, 256, 0, stream>>>(agg, hA, bt[4], bt[5], b_rel3, hB);

    // pooling + head
    hipMemsetAsync(gsum, 0, (size_t)NG * 4, stream);
    hipMemsetAsync(gcnt, 0, (size_t)NG * 4, stream);
    k_pool<<<aggGrid, 256, 0, stream>>>(hB, batch, w_out, gsum, gcnt);
    k_final<<<(NG + 255) / 256, 256, 0, stream>>>(gsum, gcnt, b_out, out);
}